// Round 12
// baseline (7174.221 us; speedup 1.0000x reference)
//
#include <hip/hip_runtime.h>

// StructLNN: LN(67) -> Linear(67,256)+LN+SiLU -> CfC scan (2048 steps) -> LN head -> [B,S,1]
//   prep: repack weights (W_x^T bf16 for GEMM; W_h int8 quant as per-wave MFMA B-fragments)
//   k2 feat_kernel: input LN + MFMA proj + LN + SiLU -> feat bf16
//   k3 gemm_kernel: pre = feat @ W_x^T + bias4; GATE-INTERLEAVED layout [bg][cs][bl][j][g]
//   k4 scan_kernel: batch-packed MFMA scan, 8 WGs x 16 batches. Weights in PHYSICAL AGPRs
//      (r2-r5: RA spills compiler-managed weights; r7: VOP3P can't read AGPR -> MFMA B=a[..]).
//      256 MFMA/WG/step (zero redundancy, 1280cyc/CU floor). r11 was VALU-issue-bound
//      (81% local VALUBusy): 32 scalar conflicted LDS reads + heavy per-step addressing.
//      r12: ds_read_b64 gate-sets (8 reads), precomputed offsets, dt in regs, triple-buf
//      preT with counted vmcnt(16) -> gate phase ~3x fewer VALU ops.
//   k5 head_kernel: folded LN+head over hseq (memory-bound).

typedef __bf16 bf16x8 __attribute__((ext_vector_type(8)));
typedef float f32x4 __attribute__((ext_vector_type(4)));
typedef int i32x4 __attribute__((ext_vector_type(4)));

#define DEVFN static __device__ __forceinline__

DEVFN float bf2f(unsigned short u){ return __uint_as_float(((unsigned)u) << 16); }
DEVFN unsigned short f2bf(float f){
  unsigned x = __float_as_uint(f);
  return (unsigned short)((x + 0x7FFFu + ((x >> 16) & 1u)) >> 16);
}
DEVFN float sigm(float x){ return 1.f / (1.f + __expf(-x)); }
DEVFN float tanh_f(float x){ return 1.f - 2.f / (__expf(2.f * x) + 1.f); }

#define GLD_LDS16(g, l) \
  __builtin_amdgcn_global_load_lds((const __attribute__((address_space(1))) void*)(g), \
                                   (__attribute__((address_space(3))) void*)(l), 16, 0, 0)

static constexpr int BB = 128;
static constexpr int SS = 2048;
static constexpr int DD = 67;

// ws layout (bytes)
static constexpr size_t OFF_WXT   = 0;         // bf16 [1024][256]  W_x^T (x-part of 4 mats)
static constexpr size_t OFF_WQ    = 524288;    // i8   [512 thr][32 frags][16B] W_h^T quant, MFMA-B layout
static constexpr size_t OFF_SW    = 786432;    // f32  [1024] per-column scales
static constexpr size_t OFF_BIAS4 = 790528;    // f32  [1024] concat(b_ff1,b_ff2,b_ta,b_tb)
static constexpr size_t OFF_PWT   = 794624;    // bf16 [256][96] proj_W^T zero-padded
static constexpr size_t OFF_GW    = 843776;    // f32  [256] head_g*head_W
static constexpr size_t OFF_SCAL  = 844800;    // f32  [2]: S_gW, S_bW+head_bias
static constexpr size_t OFF_HST   = 845824;    // i32  [128][64] persisted packed-int8 h
static constexpr size_t OFF_FEAT  = 878592;    // bf16 [B*C][256] (feat, then reused as hseq)

// ---------------------------------------------------------------- prep
__global__ __launch_bounds__(256) void prep_kernel(
    const float* __restrict__ proj_W,
    const float* __restrict__ W_ff1, const float* __restrict__ b_ff1,
    const float* __restrict__ W_ff2, const float* __restrict__ b_ff2,
    const float* __restrict__ W_ta,  const float* __restrict__ b_ta,
    const float* __restrict__ W_tb,  const float* __restrict__ b_tb,
    const float* __restrict__ head_g, const float* __restrict__ head_b,
    const float* __restrict__ head_W, const float* __restrict__ head_bias,
    unsigned short* __restrict__ WxT, signed char* __restrict__ wq,
    float* __restrict__ sw, float* __restrict__ bias4,
    unsigned short* __restrict__ PWT, float* __restrict__ gW, float* __restrict__ scal)
{
  __shared__ float red[8];
  int bid = blockIdx.x, t = threadIdx.x;
  int wv = t >> 6, ln = t & 63;
  if (bid < 1024) {
    int J = bid, col = J & 255, which = J >> 8;
    const float* Wsrc = which == 0 ? W_ff1 : which == 1 ? W_ff2 : which == 2 ? W_ta : W_tb;
    const float* bsrc = which == 0 ? b_ff1 : which == 1 ? b_ff2 : which == 2 ? b_ta : b_tb;
    float w = Wsrc[t * 256 + col];          // x-part rows 0..255
    WxT[J * 256 + t] = f2bf(w);
    if (t == 0) bias4[J] = bsrc[col];
  } else if (bid < 2048) {
    int J = bid - 1024, col = J & 255, which = J >> 8;
    const float* Wsrc = which == 0 ? W_ff1 : which == 1 ? W_ff2 : which == 2 ? W_ta : W_tb;
    float w = Wsrc[(256 + t) * 256 + col];  // h-part rows 256..511, k = t
    float a = fabsf(w);
    for (int m = 32; m >= 1; m >>= 1) a = fmaxf(a, __shfl_xor(a, m, 64));
    if (ln == 0) red[wv] = a;
    __syncthreads();
    a = fmaxf(fmaxf(red[0], red[1]), fmaxf(red[2], red[3]));
    float scale = (a > 0.f) ? a * (1.f / 127.f) : 1.f;
    int q = (int)rintf(w / scale);
    q = q > 127 ? 127 : (q < -127 ? -127 : q);
    // MFMA-B layout (in-wave gates, r10/r11-verified): gate g, col j, k.
    // wave = j>>5; tt=(j>>4)&1; frag f=(g*2+tt)*4+(k>>6);
    // lane = ((k&63)>>4)*16 + (j&15); byte = k&15.
    {
      int g = which, j = col, k = t;
      int wavw = j >> 5;
      int lane = ((k & 63) >> 4) * 16 + (j & 15);
      int tt = (j >> 4) & 1;
      int f = (g * 2 + tt) * 4 + (k >> 6);
      size_t dst = (size_t)(wavw * 64 + lane) * 512 + (size_t)f * 16 + (size_t)(k & 15);
      wq[dst] = (signed char)q;
    }
    if (t == 0) sw[J] = scale;
  } else {
    for (int idx = t; idx < 256 * 96; idx += 256) {
      int j = idx / 96, d = idx % 96;
      float v = (d < DD) ? proj_W[d * 256 + j] : 0.f;
      PWT[idx] = f2bf(v);
    }
    float gw = head_g[t] * head_W[t];
    gW[t] = gw;
    float bw = head_b[t] * head_W[t];
    float s1 = gw, s2 = bw;
    for (int m = 32; m >= 1; m >>= 1) { s1 += __shfl_xor(s1, m, 64); s2 += __shfl_xor(s2, m, 64); }
    if (ln == 0) { red[wv] = s1; red[4 + wv] = s2; }
    __syncthreads();
    if (t == 0) {
      scal[0] = red[0] + red[1] + red[2] + red[3];
      scal[1] = red[4] + red[5] + red[6] + red[7] + head_bias[0];
    }
  }
}

// ---------------------------------------------------------------- k2: x -> feat
__global__ __launch_bounds__(512) void feat_kernel(
    const float* __restrict__ x, const float* __restrict__ ln_in_g, const float* __restrict__ ln_in_b,
    const float* __restrict__ proj_b, const float* __restrict__ ln_p_g, const float* __restrict__ ln_p_b,
    const unsigned short* __restrict__ PWT, unsigned short* __restrict__ feat,
    int s0, int C, int cshift)
{
  __shared__ __align__(16) unsigned short XA[64 * 104];
  __shared__ __align__(16) unsigned short XB[256 * 96];
  __shared__ float partS[64][4], partQ[64][4], statM[64], statI[64];
  int tid = threadIdx.x, w = tid >> 6, lane = tid & 63;
  int r0 = blockIdx.x * 64;

  {
    float g1v = (lane < 67) ? ln_in_g[lane] : 0.f;
    float b1v = (lane < 67) ? ln_in_b[lane] : 0.f;
    float g2v = (lane < 3) ? ln_in_g[64 + lane] : 0.f;
    float b2v = (lane < 3) ? ln_in_b[64 + lane] : 0.f;
    for (int i = 0; i < 8; ++i) {
      int rl = w * 8 + i;
      int r = r0 + rl;
      int bb = r >> cshift, cs = r & (C - 1);
      const float* xr = x + (size_t)(bb * SS + s0 + cs) * DD;
      float v0 = (lane < 67) ? xr[lane] : 0.f;
      float v1 = (lane < 3) ? xr[64 + lane] : 0.f;
      float s = v0 + v1, q = v0 * v0 + v1 * v1;
      for (int m = 32; m >= 1; m >>= 1) { s += __shfl_xor(s, m, 64); q += __shfl_xor(q, m, 64); }
      float mean = s * (1.f / 67.f);
      float var = q * (1.f / 67.f) - mean * mean;
      float inv = rsqrtf(var + 1e-5f);
      float xn0 = (v0 - mean) * inv * g1v + b1v;
      float xn1 = (v1 - mean) * inv * g2v + b2v;
      XA[rl * 104 + lane] = (lane < 67) ? f2bf(xn0) : (unsigned short)0;
      if (lane < 40) XA[rl * 104 + 64 + lane] = (lane < 3) ? f2bf(xn1) : (unsigned short)0;
    }
  }
  {
    const unsigned int* src = (const unsigned int*)PWT;
    unsigned int* dst = (unsigned int*)XB;
    for (int idx = tid; idx < 256 * 48; idx += 512) dst[idx] = src[idx];
  }
  __syncthreads();

  int wm = w >> 2, wn = w & 3;
  f32x4 acc[2][4];
  #pragma unroll
  for (int mt = 0; mt < 2; ++mt)
    #pragma unroll
    for (int nt = 0; nt < 4; ++nt) acc[mt][nt] = (f32x4){0.f, 0.f, 0.f, 0.f};
  #pragma unroll
  for (int ks = 0; ks < 3; ++ks) {
    int k = ks * 32 + (lane >> 4) * 8;
    bf16x8 a[2], b[4];
    #pragma unroll
    for (int mt = 0; mt < 2; ++mt) {
      int row = wm * 32 + mt * 16 + (lane & 15);
      a[mt] = *reinterpret_cast<const bf16x8*>(&XA[row * 104 + k]);
    }
    #pragma unroll
    for (int nt = 0; nt < 4; ++nt) {
      int col = wn * 64 + nt * 16 + (lane & 15);
      b[nt] = *reinterpret_cast<const bf16x8*>(&XB[col * 96 + k]);
    }
    #pragma unroll
    for (int mt = 0; mt < 2; ++mt)
      #pragma unroll
      for (int nt = 0; nt < 4; ++nt)
        acc[mt][nt] = __builtin_amdgcn_mfma_f32_16x16x32_bf16(a[mt], b[nt], acc[mt][nt], 0, 0, 0);
  }
  #pragma unroll
  for (int nt = 0; nt < 4; ++nt) {
    int col = wn * 64 + nt * 16 + (lane & 15);
    float pb = proj_b[col];
    #pragma unroll
    for (int mt = 0; mt < 2; ++mt)
      #pragma unroll
      for (int r = 0; r < 4; ++r) acc[mt][nt][r] += pb;
  }
  #pragma unroll
  for (int mt = 0; mt < 2; ++mt) {
    #pragma unroll
    for (int r = 0; r < 4; ++r) {
      float s = 0.f, q = 0.f;
      #pragma unroll
      for (int nt = 0; nt < 4; ++nt) { float v = acc[mt][nt][r]; s += v; q += v * v; }
      for (int m = 1; m < 16; m <<= 1) { s += __shfl_xor(s, m, 16); q += __shfl_xor(q, m, 16); }
      if ((lane & 15) == 0) {
        int row = wm * 32 + mt * 16 + (lane >> 4) * 4 + r;
        partS[row][wn] = s; partQ[row][wn] = q;
      }
    }
  }
  __syncthreads();
  if (tid < 64) {
    float s = partS[tid][0] + partS[tid][1] + partS[tid][2] + partS[tid][3];
    float q = partQ[tid][0] + partQ[tid][1] + partQ[tid][2] + partQ[tid][3];
    float mean = s * (1.f / 256.f);
    float var = q * (1.f / 256.f) - mean * mean;
    statM[tid] = mean; statI[tid] = rsqrtf(var + 1e-5f);
  }
  __syncthreads();
  #pragma unroll
  for (int nt = 0; nt < 4; ++nt) {
    int col = wn * 64 + nt * 16 + (lane & 15);
    float gc = ln_p_g[col], bc = ln_p_b[col];
    #pragma unroll
    for (int mt = 0; mt < 2; ++mt)
      #pragma unroll
      for (int r = 0; r < 4; ++r) {
        int row = wm * 32 + mt * 16 + (lane >> 4) * 4 + r;
        float v = acc[mt][nt][r];
        float y = (v - statM[row]) * statI[row] * gc + bc;
        float sl = y * sigm(y);
        feat[(size_t)(r0 + row) * 256 + col] = f2bf(sl);
      }
  }
}

// ---------------------------------------------------------------- k3: pre = feat @ WxT + bias4
// Gate-interleaved output: pre3[(((bg*C + cs)*16 + bl)*256 + j)*4 + g]  (u16)
__global__ __launch_bounds__(256, 2) void gemm_kernel(
    const unsigned short* __restrict__ feat, const unsigned short* __restrict__ WxT,
    const float* __restrict__ bias4, unsigned short* __restrict__ pre,
    int C, int cshift)
{
  __shared__ __align__(16) unsigned short Abuf[128 * 64];
  __shared__ __align__(16) unsigned short Bbuf[128 * 64];
  int tid = threadIdx.x, w = tid >> 6, lane = tid & 63;
  int m0 = blockIdx.x * 128, n0 = blockIdx.y * 128;
  int wm = w >> 1, wn = w & 1;
  f32x4 acc[4][4];
  #pragma unroll
  for (int i = 0; i < 4; ++i)
    #pragma unroll
    for (int j = 0; j < 4; ++j) acc[i][j] = (f32x4){0.f, 0.f, 0.f, 0.f};

  #pragma unroll 1
  for (int ks = 0; ks < 4; ++ks) {
    int k0 = ks * 64;
    #pragma unroll
    for (int i = 0; i < 4; ++i) {
      int c = i * 256 + tid;
      int row = c >> 3, cc = c & 7;
      const unsigned short* ga = feat + (size_t)(m0 + row) * 256 + (k0 + cc * 8);
      const unsigned short* gb = WxT + (size_t)(n0 + row) * 256 + (k0 + cc * 8);
      char* la = (char*)Abuf + (size_t)(i * 256 + w * 64) * 16;
      char* lb = (char*)Bbuf + (size_t)(i * 256 + w * 64) * 16;
      GLD_LDS16(ga, la);
      GLD_LDS16(gb, lb);
    }
    __syncthreads();
    #pragma unroll
    for (int kk = 0; kk < 2; ++kk) {
      int k = kk * 32 + (lane >> 4) * 8;
      bf16x8 a[4], b[4];
      #pragma unroll
      for (int mt = 0; mt < 4; ++mt) {
        int row = wm * 64 + mt * 16 + (lane & 15);
        a[mt] = *reinterpret_cast<const bf16x8*>(&Abuf[row * 64 + k]);
      }
      #pragma unroll
      for (int nt = 0; nt < 4; ++nt) {
        int col = wn * 64 + nt * 16 + (lane & 15);
        b[nt] = *reinterpret_cast<const bf16x8*>(&Bbuf[col * 64 + k]);
      }
      #pragma unroll
      for (int mt = 0; mt < 4; ++mt)
        #pragma unroll
        for (int nt = 0; nt < 4; ++nt)
          acc[mt][nt] = __builtin_amdgcn_mfma_f32_16x16x32_bf16(a[mt], b[nt], acc[mt][nt], 0, 0, 0);
    }
    __syncthreads();
  }
  #pragma unroll
  for (int nt = 0; nt < 4; ++nt) {
    int colJ = n0 + wn * 64 + nt * 16 + (lane & 15);
    float bv = bias4[colJ];
    int g = colJ >> 8, jj = colJ & 255;
    #pragma unroll
    for (int mt = 0; mt < 4; ++mt)
      #pragma unroll
      for (int r = 0; r < 4; ++r) {
        int row = m0 + wm * 64 + mt * 16 + (lane >> 4) * 4 + r;
        int bb = row >> cshift, cs2 = row & (C - 1);
        int bgy = bb >> 4, bl = bb & 15;
        pre[((((size_t)bgy * C + cs2) * 16 + bl) * 256 + jj) * 4 + g] = f2bf(acc[mt][nt][r] + bv);
      }
  }
}

// ---------------------------------------------------------------- k4: batch-packed scan, 1 WG / 16 batches
// A rows = 16 batches; B = weights in physical AGPRs (wave w: cols [w*32,(w+1)*32) x 4 gates,
// frag f=(g*2+tt), AGPR base f*16+kt*4). D: batch=(lane>>4)*4+reg, col=lane&15.
// Gate: 8 (tt,r) sets/lane, each one ds_read_b64 (4 gates interleaved).
#define WRA(n, val) asm volatile("v_accvgpr_write_b32 a" #n ", %0" :: "v"(val) : "a" #n)
#define WR4(n0,n1,n2,n3, q) \
  do { WRA(n0,(q).x); WRA(n1,(q).y); WRA(n2,(q).z); WRA(n3,(q).w); } while (0)
#define MFMA_AB(acc, af, b0, b1) \
  asm volatile("v_mfma_i32_16x16x64_i8 %0, %1, a[" #b0 ":" #b1 "], %2" \
               : "=&v"(acc) : "v"(af), "v"(acc))

__global__ __attribute__((amdgpu_flat_work_group_size(512, 512)))
           __attribute__((amdgpu_waves_per_eu(2, 2)))
void scan_kernel(
    const unsigned short* __restrict__ pre3, const float* __restrict__ dt,
    const signed char* __restrict__ wq, const float* __restrict__ sw,
    int* __restrict__ hstate, unsigned short* __restrict__ hseq,
    int s0, int C, int cshift)
{
  __shared__ __align__(16) signed char h_lds[2][16][256];      // 8 KB, XOR-swizzled cols
  __shared__ __align__(16) unsigned short preT[3][16384];      // 96 KB, triple-buffered
  int tid = threadIdx.x, w = tid >> 6, l = tid & 63;
  int bg = blockIdx.x;
  int lg = l >> 4, c = l & 15;

  // stage 128 weight dwords (32 B-fragments) into physical AGPRs a0..a127 (r10/r11-verified)
  {
    const int4* wp = (const int4*)(wq + (size_t)tid * 512);
    int4 q0, q1, q2, q3, q4, q5, q6, q7;
    q0=wp[0]; q1=wp[1]; q2=wp[2]; q3=wp[3]; q4=wp[4]; q5=wp[5]; q6=wp[6]; q7=wp[7];
    WR4(0,1,2,3,q0);     WR4(4,5,6,7,q1);     WR4(8,9,10,11,q2);    WR4(12,13,14,15,q3);
    WR4(16,17,18,19,q4); WR4(20,21,22,23,q5); WR4(24,25,26,27,q6);  WR4(28,29,30,31,q7);
    q0=wp[8]; q1=wp[9]; q2=wp[10]; q3=wp[11]; q4=wp[12]; q5=wp[13]; q6=wp[14]; q7=wp[15];
    WR4(32,33,34,35,q0); WR4(36,37,38,39,q1); WR4(40,41,42,43,q2);  WR4(44,45,46,47,q3);
    WR4(48,49,50,51,q4); WR4(52,53,54,55,q5); WR4(56,57,58,59,q6);  WR4(60,61,62,63,q7);
    q0=wp[16]; q1=wp[17]; q2=wp[18]; q3=wp[19]; q4=wp[20]; q5=wp[21]; q6=wp[22]; q7=wp[23];
    WR4(64,65,66,67,q0); WR4(68,69,70,71,q1); WR4(72,73,74,75,q2);  WR4(76,77,78,79,q3);
    WR4(80,81,82,83,q4); WR4(84,85,86,87,q5); WR4(88,89,90,91,q6);  WR4(92,93,94,95,q7);
    q0=wp[24]; q1=wp[25]; q2=wp[26]; q3=wp[27]; q4=wp[28]; q5=wp[29]; q6=wp[30]; q7=wp[31];
    WR4(96,97,98,99,q0);   WR4(100,101,102,103,q1); WR4(104,105,106,107,q2); WR4(108,109,110,111,q3);
    WR4(112,113,114,115,q4); WR4(116,117,118,119,q5); WR4(120,121,122,123,q6); WR4(124,125,126,127,q7);
  }

  // gate scales sc[tt][g]
  float sc[2][4];
  #pragma unroll
  for (int tt = 0; tt < 2; ++tt)
    #pragma unroll
    for (int g = 0; g < 4; ++g)
      sc[tt][g] = sw[g * 256 + w * 32 + tt * 16 + c] * (1.f / 127.f);

  // precomputed per-set constants: bl = lg*4+r, j = w*32+tt*16+c
  int po[2][4];                    // preT read byte offset (within buffer)
  int ho[2][4];                    // h_lds write byte offset (within buffer)
  unsigned short* hp[2][4];        // hseq base pointers (advance via cs*256)
  #pragma unroll
  for (int tt = 0; tt < 2; ++tt)
    #pragma unroll
    for (int r = 0; r < 4; ++r) {
      int bl = lg * 4 + r;
      int j = w * 32 + tt * 16 + c;
      po[tt][r] = (bl * 256 + j) * 8;
      ho[tt][r] = bl * 256 + (j ^ ((bl & 7) << 4));
      hp[tt][r] = hseq + ((size_t)(bg * 16 + bl) * C) * 256 + j;
    }
  // dt pointers + first value
  const float* dp[4];
  float dtc[4];
  #pragma unroll
  for (int r = 0; r < 4; ++r) {
    dp[r] = dt + (size_t)(bg * 16 + lg * 4 + r) * SS + s0;
    dtc[r] = dp[r][0] * 10.f;
  }

  // A-read byte offsets (within h buffer), swizzle ^((c&7)<<4)
  int aswz = (c & 7) << 4;
  int ab = c * 256;
  int ak0 = ab + ((lg * 16 +   0) ^ aswz);
  int ak1 = ab + ((lg * 16 +  64) ^ aswz);
  int ak2 = ab + ((lg * 16 + 128) ^ aswz);
  int ak3 = ab + ((lg * 16 + 192) ^ aswz);

  // stage source offsets (identity: linear copy of 32KB step-row)
  const unsigned short* preB3 = pre3 + (size_t)bg * C * 16384;
  int so0 = (w * 256 +   0 + l) * 8;
  int so1 = (w * 256 +  64 + l) * 8;
  int so2 = (w * 256 + 128 + l) * 8;
  int so3 = (w * 256 + 192 + l) * 8;
#define STAGE_PRE(cs_t, buf) do { \
    const unsigned short* _s = preB3 + (size_t)(cs_t) * 16384; \
    char* _d = (char*)&preT[0][0] + (size_t)(buf) * 32768 + w * 4096; \
    GLD_LDS16(_s + so0, _d); \
    GLD_LDS16(_s + so1, _d + 1024); \
    GLD_LDS16(_s + so2, _d + 2048); \
    GLD_LDS16(_s + so3, _d + 3072); \
  } while (0)

  // h init (swizzled: [bl][col ^ ((bl&7)<<4)])
  if (s0 == 0) {
    for (int idx = tid; idx < 1024; idx += 512) ((int*)&h_lds[0][0][0])[idx] = 0;
  } else if (tid < 256) {
    int bl = tid >> 4, blk = tid & 15;
    int4 v = *(const int4*)&hstate[(bg * 16 + bl) * 64 + blk * 4];
    *(int4*)&h_lds[0][bl][(blk * 16) ^ ((bl & 7) << 4)] = v;
  }

  STAGE_PRE(0, 0);
  STAGE_PRE(1, 1);
  asm volatile("s_waitcnt vmcnt(4)" ::: "memory");
  __syncthreads();

  int cur3 = 0, hc = 0;
  for (int cs = 0; cs < C; ++cs) {
    // A fragments from current h buffer
    const char* hb = (const char*)&h_lds[0][0][0] + hc * 4096;
    i32x4 A0 = *(const i32x4*)(hb + ak0);
    i32x4 A1 = *(const i32x4*)(hb + ak1);
    i32x4 A2 = *(const i32x4*)(hb + ak2);
    i32x4 A3 = *(const i32x4*)(hb + ak3);
    // stage 2 steps ahead into the buffer freed last step
    int sb = cur3 + 2; if (sb >= 3) sb -= 3;
    if (cs + 2 < C) STAGE_PRE(cs + 2, sb);
    // dt prefetch for next step
    float dtn[4] = {0.f, 0.f, 0.f, 0.f};
    if (cs + 1 < C) {
      #pragma unroll
      for (int r = 0; r < 4; ++r) dtn[r] = dp[r][cs + 1] * 10.f;
    }

    i32x4 c0 = {0,0,0,0}, c1 = {0,0,0,0}, c2 = {0,0,0,0}, c3 = {0,0,0,0};
    i32x4 c4 = {0,0,0,0}, c5 = {0,0,0,0}, c6 = {0,0,0,0}, c7 = {0,0,0,0};
    MFMA_AB(c0, A0,   0,   3); MFMA_AB(c1, A0,  16,  19); MFMA_AB(c2, A0,  32,  35); MFMA_AB(c3, A0,  48,  51);
    MFMA_AB(c4, A0,  64,  67); MFMA_AB(c5, A0,  80,  83); MFMA_AB(c6, A0,  96,  99); MFMA_AB(c7, A0, 112, 115);
    MFMA_AB(c0, A1,   4,   7); MFMA_AB(c1, A1,  20,  23); MFMA_AB(c2, A1,  36,  39); MFMA_AB(c3, A1,  52,  55);
    MFMA_AB(c4, A1,  68,  71); MFMA_AB(c5, A1,  84,  87); MFMA_AB(c6, A1, 100, 103); MFMA_AB(c7, A1, 116, 119);
    MFMA_AB(c0, A2,   8,  11); MFMA_AB(c1, A2,  24,  27); MFMA_AB(c2, A2,  40,  43); MFMA_AB(c3, A2,  56,  59);
    MFMA_AB(c4, A2,  72,  75); MFMA_AB(c5, A2,  88,  91); MFMA_AB(c6, A2, 104, 107); MFMA_AB(c7, A2, 120, 123);
    MFMA_AB(c0, A3,  12,  15); MFMA_AB(c1, A3,  28,  31); MFMA_AB(c2, A3,  44,  47); MFMA_AB(c3, A3,  60,  63);
    MFMA_AB(c4, A3,  76,  79); MFMA_AB(c5, A3,  92,  95); MFMA_AB(c6, A3, 108, 111); MFMA_AB(c7, A3, 124, 127);
    asm volatile("s_nop 7\n\ts_nop 7\n\ts_nop 7");   // MFMA-D -> VALU read hazard margin

    const char* pTb = (const char*)&preT[0][0] + (size_t)cur3 * 32768;
    signed char* hwb = (signed char*)&h_lds[0][0][0] + (hc ^ 1) * 4096;
    size_t hstep = (size_t)cs << 8;
    #pragma unroll
    for (int tt = 0; tt < 2; ++tt) {
      #pragma unroll
      for (int r = 0; r < 4; ++r) {
        ushort4 pv = *(const ushort4*)(pTb + po[tt][r]);
        int d0 = tt ? c1[r] : c0[r];
        int d1 = tt ? c3[r] : c2[r];
        int d2 = tt ? c5[r] : c4[r];
        int d3 = tt ? c7[r] : c6[r];
        float g0 = (float)d0 * sc[tt][0] + bf2f(pv.x);
        float g1 = (float)d1 * sc[tt][1] + bf2f(pv.y);
        float g2 = (float)d2 * sc[tt][2] + bf2f(pv.z);
        float g3 = (float)d3 * sc[tt][3] + bf2f(pv.w);
        float f1v = tanh_f(g0), f2v = tanh_f(g1);
        float ti = sigm(g2 * dtc[r] + g3);
        float h = f1v + ti * (f2v - f1v);
        int q = (int)rintf(h * 127.f);
        q = q > 127 ? 127 : (q < -127 ? -127 : q);
        hwb[ho[tt][r]] = (signed char)q;
        hp[tt][r][hstep] = f2bf(h);
      }
    }
    #pragma unroll
    for (int r = 0; r < 4; ++r) dtc[r] = dtn[r];
    // drain: leave newest 16 (this step's 4 stage + 4 dt + 8 stores) -> stage(cs+1) done.
    if (cs + 2 < C) asm volatile("s_waitcnt vmcnt(16)" ::: "memory");
    else            asm volatile("s_waitcnt vmcnt(8)"  ::: "memory");
    cur3 = (cur3 + 1 == 3) ? 0 : cur3 + 1;
    hc ^= 1;
    __syncthreads();
  }
  if (tid < 256) {
    int bl = tid >> 4, blk = tid & 15;
    int4 v = *(const int4*)&h_lds[hc][bl][(blk * 16) ^ ((bl & 7) << 4)];
    *(int4*)&hstate[(bg * 16 + bl) * 64 + blk * 4] = v;
  }
}

// ---------------------------------------------------------------- k5: head from hseq
__global__ __launch_bounds__(256) void head_kernel(
    const unsigned short* __restrict__ hseq, const float* __restrict__ gW,
    const float* __restrict__ scal, float* __restrict__ out, int s0, int C, int cshift)
{
  int tid = threadIdx.x, wv = tid >> 6, l = tid & 63;
  int row = blockIdx.x * 4 + wv;                 // row in [0, B*C)
  const unsigned short* hr = hseq + (size_t)row * 256 + l * 4;
  ushort4 u = *reinterpret_cast<const ushort4*>(hr);
  float4 gw = *reinterpret_cast<const float4*>(gW + l * 4);
  float v0 = bf2f(u.x), v1 = bf2f(u.y), v2 = bf2f(u.z), v3 = bf2f(u.w);
  float s1 = v0 + v1 + v2 + v3;
  float s2 = v0 * v0 + v1 * v1 + v2 * v2 + v3 * v3;
  float s3 = v0 * gw.x + v1 * gw.y + v2 * gw.z + v3 * gw.w;
  for (int m = 32; m >= 1; m >>= 1) {
    s1 += __shfl_xor(s1, m, 64); s2 += __shfl_xor(s2, m, 64); s3 += __shfl_xor(s3, m, 64);
  }
  if (l == 0) {
    float mean = s1 * (1.f / 256.f);
    float var = s2 * (1.f / 256.f) - mean * mean;
    float inv = rsqrtf(var + 1e-5f);
    int b = row >> cshift, cs = row & (C - 1);
    out[(size_t)b * SS + s0 + cs] = inv * (s3 - mean * scal[0]) + scal[1];
  }
}

// ---------------------------------------------------------------- launch
extern "C" void kernel_launch(void* const* d_in, const int* in_sizes, int n_in,
                              void* d_out, int out_size, void* d_ws, size_t ws_size,
                              hipStream_t stream)
{
  (void)in_sizes; (void)n_in; (void)out_size;
  const float* x        = (const float*)d_in[0];
  const float* dt       = (const float*)d_in[1];
  const float* ln_in_g  = (const float*)d_in[2];
  const float* ln_in_b  = (const float*)d_in[3];
  const float* proj_W   = (const float*)d_in[4];
  const float* proj_b   = (const float*)d_in[5];
  const float* ln_p_g   = (const float*)d_in[6];
  const float* ln_p_b   = (const float*)d_in[7];
  const float* W_ff1    = (const float*)d_in[8];
  const float* b_ff1    = (const float*)d_in[9];
  const float* W_ff2    = (const float*)d_in[10];
  const float* b_ff2    = (const float*)d_in[11];
  const float* W_ta     = (const float*)d_in[12];
  const float* b_ta     = (const float*)d_in[13];
  const float* W_tb     = (const float*)d_in[14];
  const float* b_tb     = (const float*)d_in[15];
  const float* head_g   = (const float*)d_in[16];
  const float* head_b   = (const float*)d_in[17];
  const float* head_W   = (const float*)d_in[18];
  const float* head_bias= (const float*)d_in[19];

  char* ws = (char*)d_ws;
  unsigned short* WxT = (unsigned short*)(ws + OFF_WXT);
  signed char* wq     = (signed char*)(ws + OFF_WQ);
  float* sw           = (float*)(ws + OFF_SW);
  float* bias4        = (float*)(ws + OFF_BIAS4);
  unsigned short* PWT = (unsigned short*)(ws + OFF_PWT);
  float* gWv          = (float*)(ws + OFF_GW);
  float* scal         = (float*)(ws + OFF_SCAL);
  int* hstate         = (int*)(ws + OFF_HST);

  int C = 16;
  for (int c = 512; c >= 16; c >>= 1) {
    size_t need = OFF_FEAT + (size_t)c * 65536 + (size_t)c * 262144;
    if (need <= ws_size) { C = c; break; }
  }
  unsigned short* featb = (unsigned short*)(ws + OFF_FEAT);   // feat, then hseq
  unsigned short* preb  = (unsigned short*)(ws + OFF_FEAT + (size_t)C * 65536);
  int cshift = 31 - __builtin_clz((unsigned)C);

  prep_kernel<<<2049, 256, 0, stream>>>(proj_W, W_ff1, b_ff1, W_ff2, b_ff2, W_ta, b_ta, W_tb, b_tb,
                                        head_g, head_b, head_W, head_bias,
                                        WxT, wq, sw, bias4, PWT, gWv, scal);
  int nch = SS / C;
  for (int ch = 0; ch < nch; ++ch) {
    int s0 = ch * C;
    feat_kernel<<<dim3(BB * C / 64), 512, 0, stream>>>(x, ln_in_g, ln_in_b, proj_b, ln_p_g, ln_p_b,
                                                       PWT, featb, s0, C, cshift);
    gemm_kernel<<<dim3(BB * C / 128, 8), 256, 0, stream>>>(featb, WxT, bias4, preb, C, cshift);
    scan_kernel<<<dim3(BB / 16), 512, 0, stream>>>(preb, dt, wq, sw, hstate, featb, s0, C, cshift);
    head_kernel<<<dim3(BB * C / 4), 256, 0, stream>>>(featb, gWv, scal, (float*)d_out, s0, C, cshift);
  }
}

// Round 13
// 2180.122 us; speedup vs baseline: 3.2907x; 3.2907x over previous
//
#include <hip/hip_runtime.h>

// StructLNN: LN(67) -> Linear(67,256)+LN+SiLU -> CfC scan (2048 steps) -> LN head -> [B,S,1]
//   prep: repack weights (W_x^T bf16 for GEMM; W_h int8 quant, per-wave MFMA B-fragments:
//         wave w owns cols [w*32,(w+1)*32) x ALL 4 gates)
//   k2 feat_kernel: input LN + MFMA proj + LN + SiLU -> feat bf16
//   k3 gemm_kernel: pre = feat @ W_x^T + bias4 (bf16 MFMA)
//   k4 scan_kernel: 1 WG/batch, 8 waves (r10-verified best: 546us/dispatch, 2560 cyc/step).
//      Weights in PHYSICAL AGPRs a0..a127 (r2-r5: RA spills compiler-managed storage;
//      r7: VOP3P can't read AGPR -> MFMA B=a[N:N+3]). 32 v_mfma_i32_16x16x64_i8/wave/step,
//      A = h broadcast, in-wave gate phase, ONE barrier/step, dbuf hq2.
//      r11/r12 LESSON: batch-packing does NOT cut the critical path (256 MFMA/WG/step
//      invariant); it only concentrates gate VALU onto fewer CUs (1386/1610us). Reverted.
//      r13 polish: incremental pointers for pre/dt prefetch + hseq store (no per-step muls).
//   k5 head_kernel: folded LN+head over hseq (memory-bound).

typedef __bf16 bf16x8 __attribute__((ext_vector_type(8)));
typedef float f32x4 __attribute__((ext_vector_type(4)));
typedef int i32x4 __attribute__((ext_vector_type(4)));

#define DEVFN static __device__ __forceinline__

DEVFN float bf2f(unsigned short u){ return __uint_as_float(((unsigned)u) << 16); }
DEVFN unsigned short f2bf(float f){
  unsigned x = __float_as_uint(f);
  return (unsigned short)((x + 0x7FFFu + ((x >> 16) & 1u)) >> 16);
}
DEVFN float sigm(float x){ return 1.f / (1.f + __expf(-x)); }
DEVFN float tanh_f(float x){ return 1.f - 2.f / (__expf(2.f * x) + 1.f); }

#define GLD_LDS16(g, l) \
  __builtin_amdgcn_global_load_lds((const __attribute__((address_space(1))) void*)(g), \
                                   (__attribute__((address_space(3))) void*)(l), 16, 0, 0)

static constexpr int BB = 128;
static constexpr int SS = 2048;
static constexpr int DD = 67;

// ws layout (bytes)
static constexpr size_t OFF_WXT   = 0;         // bf16 [1024][256]  W_x^T (x-part of 4 mats)
static constexpr size_t OFF_WQ    = 524288;    // i8   [512 thr][32 frags][16B] W_h^T quant, MFMA-B layout
static constexpr size_t OFF_SW    = 786432;    // f32  [1024] per-column scales
static constexpr size_t OFF_BIAS4 = 790528;    // f32  [1024] concat(b_ff1,b_ff2,b_ta,b_tb)
static constexpr size_t OFF_PWT   = 794624;    // bf16 [256][96] proj_W^T zero-padded
static constexpr size_t OFF_GW    = 843776;    // f32  [256] head_g*head_W
static constexpr size_t OFF_SCAL  = 844800;    // f32  [2]: S_gW, S_bW+head_bias
static constexpr size_t OFF_HST   = 845824;    // i32  [128][64] persisted packed-int8 h
static constexpr size_t OFF_FEAT  = 878592;    // bf16 [B*C][256] (feat, then reused as hseq)

// ---------------------------------------------------------------- prep
__global__ __launch_bounds__(256) void prep_kernel(
    const float* __restrict__ proj_W,
    const float* __restrict__ W_ff1, const float* __restrict__ b_ff1,
    const float* __restrict__ W_ff2, const float* __restrict__ b_ff2,
    const float* __restrict__ W_ta,  const float* __restrict__ b_ta,
    const float* __restrict__ W_tb,  const float* __restrict__ b_tb,
    const float* __restrict__ head_g, const float* __restrict__ head_b,
    const float* __restrict__ head_W, const float* __restrict__ head_bias,
    unsigned short* __restrict__ WxT, signed char* __restrict__ wq,
    float* __restrict__ sw, float* __restrict__ bias4,
    unsigned short* __restrict__ PWT, float* __restrict__ gW, float* __restrict__ scal)
{
  __shared__ float red[8];
  int bid = blockIdx.x, t = threadIdx.x;
  int wv = t >> 6, ln = t & 63;
  if (bid < 1024) {
    int J = bid, col = J & 255, which = J >> 8;
    const float* Wsrc = which == 0 ? W_ff1 : which == 1 ? W_ff2 : which == 2 ? W_ta : W_tb;
    const float* bsrc = which == 0 ? b_ff1 : which == 1 ? b_ff2 : which == 2 ? b_ta : b_tb;
    float w = Wsrc[t * 256 + col];          // x-part rows 0..255
    WxT[J * 256 + t] = f2bf(w);
    if (t == 0) bias4[J] = bsrc[col];
  } else if (bid < 2048) {
    int J = bid - 1024, col = J & 255, which = J >> 8;
    const float* Wsrc = which == 0 ? W_ff1 : which == 1 ? W_ff2 : which == 2 ? W_ta : W_tb;
    float w = Wsrc[(256 + t) * 256 + col];  // h-part rows 256..511, k = t
    float a = fabsf(w);
    for (int m = 32; m >= 1; m >>= 1) a = fmaxf(a, __shfl_xor(a, m, 64));
    if (ln == 0) red[wv] = a;
    __syncthreads();
    a = fmaxf(fmaxf(red[0], red[1]), fmaxf(red[2], red[3]));
    float scale = (a > 0.f) ? a * (1.f / 127.f) : 1.f;
    int q = (int)rintf(w / scale);
    q = q > 127 ? 127 : (q < -127 ? -127 : q);
    // MFMA-B layout (in-wave gates, r10-verified): gate g, col j, k.
    // wave = j>>5; tt=(j>>4)&1; frag f=(g*2+tt)*4+(k>>6);
    // lane = ((k&63)>>4)*16 + (j&15); byte = k&15.
    {
      int g = which, j = col, k = t;
      int wavw = j >> 5;
      int lane = ((k & 63) >> 4) * 16 + (j & 15);
      int tt = (j >> 4) & 1;
      int f = (g * 2 + tt) * 4 + (k >> 6);
      size_t dst = (size_t)(wavw * 64 + lane) * 512 + (size_t)f * 16 + (size_t)(k & 15);
      wq[dst] = (signed char)q;
    }
    if (t == 0) sw[J] = scale;
  } else {
    for (int idx = t; idx < 256 * 96; idx += 256) {
      int j = idx / 96, d = idx % 96;
      float v = (d < DD) ? proj_W[d * 256 + j] : 0.f;
      PWT[idx] = f2bf(v);
    }
    float gw = head_g[t] * head_W[t];
    gW[t] = gw;
    float bw = head_b[t] * head_W[t];
    float s1 = gw, s2 = bw;
    for (int m = 32; m >= 1; m >>= 1) { s1 += __shfl_xor(s1, m, 64); s2 += __shfl_xor(s2, m, 64); }
    if (ln == 0) { red[wv] = s1; red[4 + wv] = s2; }
    __syncthreads();
    if (t == 0) {
      scal[0] = red[0] + red[1] + red[2] + red[3];
      scal[1] = red[4] + red[5] + red[6] + red[7] + head_bias[0];
    }
  }
}

// ---------------------------------------------------------------- k2: x -> feat
__global__ __launch_bounds__(512) void feat_kernel(
    const float* __restrict__ x, const float* __restrict__ ln_in_g, const float* __restrict__ ln_in_b,
    const float* __restrict__ proj_b, const float* __restrict__ ln_p_g, const float* __restrict__ ln_p_b,
    const unsigned short* __restrict__ PWT, unsigned short* __restrict__ feat,
    int s0, int C, int cshift)
{
  __shared__ __align__(16) unsigned short XA[64 * 104];
  __shared__ __align__(16) unsigned short XB[256 * 96];
  __shared__ float partS[64][4], partQ[64][4], statM[64], statI[64];
  int tid = threadIdx.x, w = tid >> 6, lane = tid & 63;
  int r0 = blockIdx.x * 64;

  {
    float g1v = (lane < 67) ? ln_in_g[lane] : 0.f;
    float b1v = (lane < 67) ? ln_in_b[lane] : 0.f;
    float g2v = (lane < 3) ? ln_in_g[64 + lane] : 0.f;
    float b2v = (lane < 3) ? ln_in_b[64 + lane] : 0.f;
    for (int i = 0; i < 8; ++i) {
      int rl = w * 8 + i;
      int r = r0 + rl;
      int bb = r >> cshift, cs = r & (C - 1);
      const float* xr = x + (size_t)(bb * SS + s0 + cs) * DD;
      float v0 = (lane < 67) ? xr[lane] : 0.f;
      float v1 = (lane < 3) ? xr[64 + lane] : 0.f;
      float s = v0 + v1, q = v0 * v0 + v1 * v1;
      for (int m = 32; m >= 1; m >>= 1) { s += __shfl_xor(s, m, 64); q += __shfl_xor(q, m, 64); }
      float mean = s * (1.f / 67.f);
      float var = q * (1.f / 67.f) - mean * mean;
      float inv = rsqrtf(var + 1e-5f);
      float xn0 = (v0 - mean) * inv * g1v + b1v;
      float xn1 = (v1 - mean) * inv * g2v + b2v;
      XA[rl * 104 + lane] = (lane < 67) ? f2bf(xn0) : (unsigned short)0;
      if (lane < 40) XA[rl * 104 + 64 + lane] = (lane < 3) ? f2bf(xn1) : (unsigned short)0;
    }
  }
  {
    const unsigned int* src = (const unsigned int*)PWT;
    unsigned int* dst = (unsigned int*)XB;
    for (int idx = tid; idx < 256 * 48; idx += 512) dst[idx] = src[idx];
  }
  __syncthreads();

  int wm = w >> 2, wn = w & 3;
  f32x4 acc[2][4];
  #pragma unroll
  for (int mt = 0; mt < 2; ++mt)
    #pragma unroll
    for (int nt = 0; nt < 4; ++nt) acc[mt][nt] = (f32x4){0.f, 0.f, 0.f, 0.f};
  #pragma unroll
  for (int ks = 0; ks < 3; ++ks) {
    int k = ks * 32 + (lane >> 4) * 8;
    bf16x8 a[2], b[4];
    #pragma unroll
    for (int mt = 0; mt < 2; ++mt) {
      int row = wm * 32 + mt * 16 + (lane & 15);
      a[mt] = *reinterpret_cast<const bf16x8*>(&XA[row * 104 + k]);
    }
    #pragma unroll
    for (int nt = 0; nt < 4; ++nt) {
      int col = wn * 64 + nt * 16 + (lane & 15);
      b[nt] = *reinterpret_cast<const bf16x8*>(&XB[col * 96 + k]);
    }
    #pragma unroll
    for (int mt = 0; mt < 2; ++mt)
      #pragma unroll
      for (int nt = 0; nt < 4; ++nt)
        acc[mt][nt] = __builtin_amdgcn_mfma_f32_16x16x32_bf16(a[mt], b[nt], acc[mt][nt], 0, 0, 0);
  }
  #pragma unroll
  for (int nt = 0; nt < 4; ++nt) {
    int col = wn * 64 + nt * 16 + (lane & 15);
    float pb = proj_b[col];
    #pragma unroll
    for (int mt = 0; mt < 2; ++mt)
      #pragma unroll
      for (int r = 0; r < 4; ++r) acc[mt][nt][r] += pb;
  }
  #pragma unroll
  for (int mt = 0; mt < 2; ++mt) {
    #pragma unroll
    for (int r = 0; r < 4; ++r) {
      float s = 0.f, q = 0.f;
      #pragma unroll
      for (int nt = 0; nt < 4; ++nt) { float v = acc[mt][nt][r]; s += v; q += v * v; }
      for (int m = 1; m < 16; m <<= 1) { s += __shfl_xor(s, m, 16); q += __shfl_xor(q, m, 16); }
      if ((lane & 15) == 0) {
        int row = wm * 32 + mt * 16 + (lane >> 4) * 4 + r;
        partS[row][wn] = s; partQ[row][wn] = q;
      }
    }
  }
  __syncthreads();
  if (tid < 64) {
    float s = partS[tid][0] + partS[tid][1] + partS[tid][2] + partS[tid][3];
    float q = partQ[tid][0] + partQ[tid][1] + partQ[tid][2] + partQ[tid][3];
    float mean = s * (1.f / 256.f);
    float var = q * (1.f / 256.f) - mean * mean;
    statM[tid] = mean; statI[tid] = rsqrtf(var + 1e-5f);
  }
  __syncthreads();
  #pragma unroll
  for (int nt = 0; nt < 4; ++nt) {
    int col = wn * 64 + nt * 16 + (lane & 15);
    float gc = ln_p_g[col], bc = ln_p_b[col];
    #pragma unroll
    for (int mt = 0; mt < 2; ++mt)
      #pragma unroll
      for (int r = 0; r < 4; ++r) {
        int row = wm * 32 + mt * 16 + (lane >> 4) * 4 + r;
        float v = acc[mt][nt][r];
        float y = (v - statM[row]) * statI[row] * gc + bc;
        float sl = y * sigm(y);
        feat[(size_t)(r0 + row) * 256 + col] = f2bf(sl);
      }
  }
}

// ---------------------------------------------------------------- k3: pre = feat @ WxT + bias4
__global__ __launch_bounds__(256, 2) void gemm_kernel(
    const unsigned short* __restrict__ feat, const unsigned short* __restrict__ WxT,
    const float* __restrict__ bias4, unsigned short* __restrict__ pre)
{
  __shared__ __align__(16) unsigned short Abuf[128 * 64];
  __shared__ __align__(16) unsigned short Bbuf[128 * 64];
  int tid = threadIdx.x, w = tid >> 6, lane = tid & 63;
  int m0 = blockIdx.x * 128, n0 = blockIdx.y * 128;
  int wm = w >> 1, wn = w & 1;
  f32x4 acc[4][4];
  #pragma unroll
  for (int i = 0; i < 4; ++i)
    #pragma unroll
    for (int j = 0; j < 4; ++j) acc[i][j] = (f32x4){0.f, 0.f, 0.f, 0.f};

  #pragma unroll 1
  for (int ks = 0; ks < 4; ++ks) {
    int k0 = ks * 64;
    #pragma unroll
    for (int i = 0; i < 4; ++i) {
      int c = i * 256 + tid;
      int row = c >> 3, cc = c & 7;
      const unsigned short* ga = feat + (size_t)(m0 + row) * 256 + (k0 + cc * 8);
      const unsigned short* gb = WxT + (size_t)(n0 + row) * 256 + (k0 + cc * 8);
      char* la = (char*)Abuf + (size_t)(i * 256 + w * 64) * 16;
      char* lb = (char*)Bbuf + (size_t)(i * 256 + w * 64) * 16;
      GLD_LDS16(ga, la);
      GLD_LDS16(gb, lb);
    }
    __syncthreads();
    #pragma unroll
    for (int kk = 0; kk < 2; ++kk) {
      int k = kk * 32 + (lane >> 4) * 8;
      bf16x8 a[4], b[4];
      #pragma unroll
      for (int mt = 0; mt < 4; ++mt) {
        int row = wm * 64 + mt * 16 + (lane & 15);
        a[mt] = *reinterpret_cast<const bf16x8*>(&Abuf[row * 64 + k]);
      }
      #pragma unroll
      for (int nt = 0; nt < 4; ++nt) {
        int col = wn * 64 + nt * 16 + (lane & 15);
        b[nt] = *reinterpret_cast<const bf16x8*>(&Bbuf[col * 64 + k]);
      }
      #pragma unroll
      for (int mt = 0; mt < 4; ++mt)
        #pragma unroll
        for (int nt = 0; nt < 4; ++nt)
          acc[mt][nt] = __builtin_amdgcn_mfma_f32_16x16x32_bf16(a[mt], b[nt], acc[mt][nt], 0, 0, 0);
    }
    __syncthreads();
  }
  #pragma unroll
  for (int nt = 0; nt < 4; ++nt) {
    int col = n0 + wn * 64 + nt * 16 + (lane & 15);
    float bv = bias4[col];
    #pragma unroll
    for (int mt = 0; mt < 4; ++mt)
      #pragma unroll
      for (int r = 0; r < 4; ++r) {
        int row = m0 + wm * 64 + mt * 16 + (lane >> 4) * 4 + r;
        pre[(size_t)row * 1024 + col] = f2bf(acc[mt][nt][r] + bv);
      }
  }
}

// ---------------------------------------------------------------- k4: recurrent scan, 1 WG/batch
// Wave w owns cols [w*32,(w+1)*32) x all 4 gates. B fragments in physical AGPRs:
// frag f=(g*2+tt) at a[f*16+kt*4 .. +3]. Per step: A = h broadcast, 32 MFMA; gate phase
// reads own c regs (no cross-wave exchange); ONE barrier/step via double-buffered hq2.
#define WRA(n, val) asm volatile("v_accvgpr_write_b32 a" #n ", %0" :: "v"(val) : "a" #n)
#define WR4(n0,n1,n2,n3, q) \
  do { WRA(n0,(q).x); WRA(n1,(q).y); WRA(n2,(q).z); WRA(n3,(q).w); } while (0)
#define MFMA_AB(acc, af, b0, b1) \
  asm volatile("v_mfma_i32_16x16x64_i8 %0, %1, a[" #b0 ":" #b1 "], %2" \
               : "=&v"(acc) : "v"(af), "v"(acc))

__global__ __attribute__((amdgpu_flat_work_group_size(512, 512)))
           __attribute__((amdgpu_waves_per_eu(2, 2)))
void scan_kernel(
    const unsigned short* __restrict__ pre, const float* __restrict__ dt,
    const signed char* __restrict__ wq, const float* __restrict__ sw,
    int* __restrict__ hstate, unsigned short* __restrict__ hseq, int s0, int C)
{
  __shared__ __align__(16) signed char hq2[2][256];
  int tid = threadIdx.x, w = tid >> 6, l = tid & 63;
  int b = blockIdx.x;

  // stage 128 weight dwords (32 B-fragments) into physical AGPRs a0..a127
  {
    const int4* wp = (const int4*)(wq + (size_t)tid * 512);
    int4 q0, q1, q2, q3, q4, q5, q6, q7;
    q0=wp[0]; q1=wp[1]; q2=wp[2]; q3=wp[3]; q4=wp[4]; q5=wp[5]; q6=wp[6]; q7=wp[7];
    WR4(0,1,2,3,q0);     WR4(4,5,6,7,q1);     WR4(8,9,10,11,q2);    WR4(12,13,14,15,q3);
    WR4(16,17,18,19,q4); WR4(20,21,22,23,q5); WR4(24,25,26,27,q6);  WR4(28,29,30,31,q7);
    q0=wp[8]; q1=wp[9]; q2=wp[10]; q3=wp[11]; q4=wp[12]; q5=wp[13]; q6=wp[14]; q7=wp[15];
    WR4(32,33,34,35,q0); WR4(36,37,38,39,q1); WR4(40,41,42,43,q2);  WR4(44,45,46,47,q3);
    WR4(48,49,50,51,q4); WR4(52,53,54,55,q5); WR4(56,57,58,59,q6);  WR4(60,61,62,63,q7);
    q0=wp[16]; q1=wp[17]; q2=wp[18]; q3=wp[19]; q4=wp[20]; q5=wp[21]; q6=wp[22]; q7=wp[23];
    WR4(64,65,66,67,q0); WR4(68,69,70,71,q1); WR4(72,73,74,75,q2);  WR4(76,77,78,79,q3);
    WR4(80,81,82,83,q4); WR4(84,85,86,87,q5); WR4(88,89,90,91,q6);  WR4(92,93,94,95,q7);
    q0=wp[24]; q1=wp[25]; q2=wp[26]; q3=wp[27]; q4=wp[28]; q5=wp[29]; q6=wp[30]; q7=wp[31];
    WR4(96,97,98,99,q0);   WR4(100,101,102,103,q1); WR4(104,105,106,107,q2); WR4(108,109,110,111,q3);
    WR4(112,113,114,115,q4); WR4(116,117,118,119,q5); WR4(120,121,122,123,q6); WR4(124,125,126,127,q7);
  }

  // gate-phase lanes: lg<2; tt=lg; col j = w*32 + tt*16 + (l&15)
  int lg = l >> 4;
  int tt = lg & 1;
  bool gact = (lg < 2);
  int j = w * 32 + tt * 16 + (l & 15);

  float sc0 = 0.f, sc1 = 0.f, sc2 = 0.f, sc3 = 0.f;
  unsigned short pu0 = 0, pu1 = 0, pu2 = 0, pu3 = 0;
  float dtc = 0.f;
  const unsigned short* preB = pre + (size_t)b * C * 1024;
  unsigned short* hsB = hseq + (size_t)b * C * 256;
  // incremental pointers (r13: no per-step cs* multiplies)
  const unsigned short* pn = preB + 1024;     // prefetch source for step cs+1
  const float* dtp = dt + (size_t)b * SS + s0 + 1;
  unsigned short* hsp = hsB;                  // store base for step cs
  if (gact) {
    sc0 = sw[j]       * (1.f / 127.f);
    sc1 = sw[256 + j] * (1.f / 127.f);
    sc2 = sw[512 + j] * (1.f / 127.f);
    sc3 = sw[768 + j] * (1.f / 127.f);
    pu0 = preB[j]; pu1 = preB[256 + j]; pu2 = preB[512 + j]; pu3 = preB[768 + j];
    dtc = dtp[-1] * 10.f;
  }

  if (tid < 64) ((int*)hq2[0])[tid] = (s0 == 0) ? 0 : hstate[b * 64 + tid];
  int cur = 0;
  __syncthreads();

  for (int cs = 0; cs < C; ++cs) {
    // A fragments: h broadcast, 16 bytes per 16-lane group per K-tile
    const signed char* hb = hq2[cur];
    int aoff = lg << 4;
    i32x4 A0 = *reinterpret_cast<const i32x4*>(hb + 0 * 64 + aoff);
    i32x4 A1 = *reinterpret_cast<const i32x4*>(hb + 1 * 64 + aoff);
    i32x4 A2 = *reinterpret_cast<const i32x4*>(hb + 2 * 64 + aoff);
    i32x4 A3 = *reinterpret_cast<const i32x4*>(hb + 3 * 64 + aoff);
    i32x4 c0 = {0,0,0,0}, c1 = {0,0,0,0}, c2 = {0,0,0,0}, c3 = {0,0,0,0};
    i32x4 c4 = {0,0,0,0}, c5 = {0,0,0,0}, c6 = {0,0,0,0}, c7 = {0,0,0,0};
    // c_f = fragment f=(g*2+tt); AGPR base = f*16 + kt*4
    MFMA_AB(c0, A0,   0,   3); MFMA_AB(c1, A0,  16,  19); MFMA_AB(c2, A0,  32,  35); MFMA_AB(c3, A0,  48,  51);
    MFMA_AB(c4, A0,  64,  67); MFMA_AB(c5, A0,  80,  83); MFMA_AB(c6, A0,  96,  99); MFMA_AB(c7, A0, 112, 115);
    MFMA_AB(c0, A1,   4,   7); MFMA_AB(c1, A1,  20,  23); MFMA_AB(c2, A1,  36,  39); MFMA_AB(c3, A1,  52,  55);
    MFMA_AB(c4, A1,  68,  71); MFMA_AB(c5, A1,  84,  87); MFMA_AB(c6, A1, 100, 103); MFMA_AB(c7, A1, 116, 119);
    MFMA_AB(c0, A2,   8,  11); MFMA_AB(c1, A2,  24,  27); MFMA_AB(c2, A2,  40,  43); MFMA_AB(c3, A2,  56,  59);
    MFMA_AB(c4, A2,  72,  75); MFMA_AB(c5, A2,  88,  91); MFMA_AB(c6, A2, 104, 107); MFMA_AB(c7, A2, 120, 123);
    MFMA_AB(c0, A3,  12,  15); MFMA_AB(c1, A3,  28,  31); MFMA_AB(c2, A3,  44,  47); MFMA_AB(c3, A3,  60,  63);
    MFMA_AB(c4, A3,  76,  79); MFMA_AB(c5, A3,  92,  95); MFMA_AB(c6, A3, 108, 111); MFMA_AB(c7, A3, 124, 127);
    asm volatile("s_nop 7\n\ts_nop 7\n\ts_nop 7");   // MFMA-D -> VALU read hazard margin
    if (gact) {
      int d0 = tt ? c1.x : c0.x;
      int d1 = tt ? c3.x : c2.x;
      int d2 = tt ? c5.x : c4.x;
      int d3 = tt ? c7.x : c6.x;
      float g0 = (float)d0 * sc0 + bf2f(pu0);
      float g1 = (float)d1 * sc1 + bf2f(pu1);
      float g2 = (float)d2 * sc2 + bf2f(pu2);
      float g3 = (float)d3 * sc3 + bf2f(pu3);
      float f1 = tanh_f(g0), f2 = tanh_f(g1);
      float ti = sigm(g2 * dtc + g3);
      float h = f1 + ti * (f2 - f1);
      int q = (int)rintf(h * 127.f);
      q = q > 127 ? 127 : (q < -127 ? -127 : q);
      hq2[cur ^ 1][j] = (signed char)q;
      hsp[j] = f2bf(h);
      if (cs + 1 < C) {   // prefetch next step (independent of barrier)
        pu0 = pn[j]; pu1 = pn[256 + j]; pu2 = pn[512 + j]; pu3 = pn[768 + j];
        dtc = dtp[0] * 10.f;
      }
    }
    pn += 1024; dtp += 1; hsp += 256;
    cur ^= 1;
    __syncthreads();
  }
  if (tid < 64) hstate[b * 64 + tid] = ((const int*)hq2[cur])[tid];
}

// ---------------------------------------------------------------- k5: head from hseq
__global__ __launch_bounds__(256) void head_kernel(
    const unsigned short* __restrict__ hseq, const float* __restrict__ gW,
    const float* __restrict__ scal, float* __restrict__ out, int s0, int C, int cshift)
{
  int tid = threadIdx.x, wv = tid >> 6, l = tid & 63;
  int row = blockIdx.x * 4 + wv;                 // row in [0, B*C)
  const unsigned short* hr = hseq + (size_t)row * 256 + l * 4;
  ushort4 u = *reinterpret_cast<const ushort4*>(hr);
  float4 gw = *reinterpret_cast<const float4*>(gW + l * 4);
  float v0 = bf2f(u.x), v1 = bf2f(u.y), v2 = bf2f(u.z), v3 = bf2f(u.w);
  float s1 = v0 + v1 + v2 + v3;
  float s2 = v0 * v0 + v1 * v1 + v2 * v2 + v3 * v3;
  float s3 = v0 * gw.x + v1 * gw.y + v2 * gw.z + v3 * gw.w;
  for (int m = 32; m >= 1; m >>= 1) {
    s1 += __shfl_xor(s1, m, 64); s2 += __shfl_xor(s2, m, 64); s3 += __shfl_xor(s3, m, 64);
  }
  if (l == 0) {
    float mean = s1 * (1.f / 256.f);
    float var = s2 * (1.f / 256.f) - mean * mean;
    float inv = rsqrtf(var + 1e-5f);
    int b = row >> cshift, cs = row & (C - 1);
    out[(size_t)b * SS + s0 + cs] = inv * (s3 - mean * scal[0]) + scal[1];
  }
}

// ---------------------------------------------------------------- launch
extern "C" void kernel_launch(void* const* d_in, const int* in_sizes, int n_in,
                              void* d_out, int out_size, void* d_ws, size_t ws_size,
                              hipStream_t stream)
{
  (void)in_sizes; (void)n_in; (void)out_size;
  const float* x        = (const float*)d_in[0];
  const float* dt       = (const float*)d_in[1];
  const float* ln_in_g  = (const float*)d_in[2];
  const float* ln_in_b  = (const float*)d_in[3];
  const float* proj_W   = (const float*)d_in[4];
  const float* proj_b   = (const float*)d_in[5];
  const float* ln_p_g   = (const float*)d_in[6];
  const float* ln_p_b   = (const float*)d_in[7];
  const float* W_ff1    = (const float*)d_in[8];
  const float* b_ff1    = (const float*)d_in[9];
  const float* W_ff2    = (const float*)d_in[10];
  const float* b_ff2    = (const float*)d_in[11];
  const float* W_ta     = (const float*)d_in[12];
  const float* b_ta     = (const float*)d_in[13];
  const float* W_tb     = (const float*)d_in[14];
  const float* b_tb     = (const float*)d_in[15];
  const float* head_g   = (const float*)d_in[16];
  const float* head_b   = (const float*)d_in[17];
  const float* head_W   = (const float*)d_in[18];
  const float* head_bias= (const float*)d_in[19];

  char* ws = (char*)d_ws;
  unsigned short* WxT = (unsigned short*)(ws + OFF_WXT);
  signed char* wq     = (signed char*)(ws + OFF_WQ);
  float* sw           = (float*)(ws + OFF_SW);
  float* bias4        = (float*)(ws + OFF_BIAS4);
  unsigned short* PWT = (unsigned short*)(ws + OFF_PWT);
  float* gWv          = (float*)(ws + OFF_GW);
  float* scal         = (float*)(ws + OFF_SCAL);
  int* hstate         = (int*)(ws + OFF_HST);

  int C = 16;
  for (int c = 2048; c >= 16; c >>= 1) {
    size_t need = OFF_FEAT + (size_t)c * 65536 + (size_t)c * 262144;
    if (need <= ws_size) { C = c; break; }
  }
  unsigned short* featb = (unsigned short*)(ws + OFF_FEAT);   // feat, then hseq
  unsigned short* preb  = (unsigned short*)(ws + OFF_FEAT + (size_t)C * 65536);
  int cshift = 31 - __builtin_clz((unsigned)C);

  prep_kernel<<<2049, 256, 0, stream>>>(proj_W, W_ff1, b_ff1, W_ff2, b_ff2, W_ta, b_ta, W_tb, b_tb,
                                        head_g, head_b, head_W, head_bias,
                                        WxT, wq, sw, bias4, PWT, gWv, scal);
  int nch = SS / C;
  for (int ch = 0; ch < nch; ++ch) {
    int s0 = ch * C;
    feat_kernel<<<dim3(BB * C / 64), 512, 0, stream>>>(x, ln_in_g, ln_in_b, proj_b, ln_p_g, ln_p_b,
                                                       PWT, featb, s0, C, cshift);
    gemm_kernel<<<dim3(BB * C / 128, 8), 256, 0, stream>>>(featb, WxT, bias4, preb);
    scan_kernel<<<dim3(BB), 512, 0, stream>>>(preb, dt, wq, sw, hstate, featb, s0, C);
    head_kernel<<<dim3(BB * C / 4), 256, 0, stream>>>(featb, gWv, scal, (float*)d_out, s0, C, cshift);
  }
}

// Round 14
// 2179.718 us; speedup vs baseline: 3.2914x; 1.0002x over previous
//
#include <hip/hip_runtime.h>

// StructLNN: LN(67) -> Linear(67,256)+LN+SiLU -> CfC scan (2048 steps) -> LN head -> [B,S,1]
//   prep: repack weights (W_x^T bf16 for GEMM; W_h int8 quant, per-wave MFMA B-fragments:
//         wave w owns cols [w*32,(w+1)*32) x ALL 4 gates)
//   k2 feat_kernel: input LN + MFMA proj + LN + SiLU -> feat bf16
//   k3 gemm_kernel: pre = feat @ W_x^T + bias4 (bf16 MFMA)
//   k4 scan_kernel: 1 WG/batch, 8 waves (r13: 456us/dispatch, 2140 cyc/step).
//      Weights in PHYSICAL AGPRs a0..a127 (r2-r5: RA spills compiler-managed storage;
//      r7: VOP3P can't read AGPR -> MFMA B=a[N:N+3]). 32 v_mfma_i32_16x16x64_i8/wave/step,
//      A = h broadcast, in-wave gate phase, ONE barrier/step, dbuf hq2.
//      r14: counted-wait barrier (T4): lgkmcnt(0)+sched_barrier+raw s_barrier instead of
//      __syncthreads -> hseq stores + pre prefetch loads stay in flight across the barrier
//      (syncthreads forced vmcnt(0) drain ~200-400cyc/step of store latency on the path).
//      r11/r12 LESSON: batch-packing can't cut the per-step critical path (256 MFMA/WG/step
//      invariant); it only concentrates gate VALU onto fewer CUs. Reverted in r13.
//   k5 head_kernel: folded LN+head over hseq (memory-bound).

typedef __bf16 bf16x8 __attribute__((ext_vector_type(8)));
typedef float f32x4 __attribute__((ext_vector_type(4)));
typedef int i32x4 __attribute__((ext_vector_type(4)));

#define DEVFN static __device__ __forceinline__

DEVFN float bf2f(unsigned short u){ return __uint_as_float(((unsigned)u) << 16); }
DEVFN unsigned short f2bf(float f){
  unsigned x = __float_as_uint(f);
  return (unsigned short)((x + 0x7FFFu + ((x >> 16) & 1u)) >> 16);
}
DEVFN float sigm(float x){ return 1.f / (1.f + __expf(-x)); }
DEVFN float tanh_f(float x){ return 1.f - 2.f / (__expf(2.f * x) + 1.f); }

#define GLD_LDS16(g, l) \
  __builtin_amdgcn_global_load_lds((const __attribute__((address_space(1))) void*)(g), \
                                   (__attribute__((address_space(3))) void*)(l), 16, 0, 0)

static constexpr int BB = 128;
static constexpr int SS = 2048;
static constexpr int DD = 67;

// ws layout (bytes)
static constexpr size_t OFF_WXT   = 0;         // bf16 [1024][256]  W_x^T (x-part of 4 mats)
static constexpr size_t OFF_WQ    = 524288;    // i8   [512 thr][32 frags][16B] W_h^T quant, MFMA-B layout
static constexpr size_t OFF_SW    = 786432;    // f32  [1024] per-column scales
static constexpr size_t OFF_BIAS4 = 790528;    // f32  [1024] concat(b_ff1,b_ff2,b_ta,b_tb)
static constexpr size_t OFF_PWT   = 794624;    // bf16 [256][96] proj_W^T zero-padded
static constexpr size_t OFF_GW    = 843776;    // f32  [256] head_g*head_W
static constexpr size_t OFF_SCAL  = 844800;    // f32  [2]: S_gW, S_bW+head_bias
static constexpr size_t OFF_HST   = 845824;    // i32  [128][64] persisted packed-int8 h
static constexpr size_t OFF_FEAT  = 878592;    // bf16 [B*C][256] (feat, then reused as hseq)

// ---------------------------------------------------------------- prep
__global__ __launch_bounds__(256) void prep_kernel(
    const float* __restrict__ proj_W,
    const float* __restrict__ W_ff1, const float* __restrict__ b_ff1,
    const float* __restrict__ W_ff2, const float* __restrict__ b_ff2,
    const float* __restrict__ W_ta,  const float* __restrict__ b_ta,
    const float* __restrict__ W_tb,  const float* __restrict__ b_tb,
    const float* __restrict__ head_g, const float* __restrict__ head_b,
    const float* __restrict__ head_W, const float* __restrict__ head_bias,
    unsigned short* __restrict__ WxT, signed char* __restrict__ wq,
    float* __restrict__ sw, float* __restrict__ bias4,
    unsigned short* __restrict__ PWT, float* __restrict__ gW, float* __restrict__ scal)
{
  __shared__ float red[8];
  int bid = blockIdx.x, t = threadIdx.x;
  int wv = t >> 6, ln = t & 63;
  if (bid < 1024) {
    int J = bid, col = J & 255, which = J >> 8;
    const float* Wsrc = which == 0 ? W_ff1 : which == 1 ? W_ff2 : which == 2 ? W_ta : W_tb;
    const float* bsrc = which == 0 ? b_ff1 : which == 1 ? b_ff2 : which == 2 ? b_ta : b_tb;
    float w = Wsrc[t * 256 + col];          // x-part rows 0..255
    WxT[J * 256 + t] = f2bf(w);
    if (t == 0) bias4[J] = bsrc[col];
  } else if (bid < 2048) {
    int J = bid - 1024, col = J & 255, which = J >> 8;
    const float* Wsrc = which == 0 ? W_ff1 : which == 1 ? W_ff2 : which == 2 ? W_ta : W_tb;
    float w = Wsrc[(256 + t) * 256 + col];  // h-part rows 256..511, k = t
    float a = fabsf(w);
    for (int m = 32; m >= 1; m >>= 1) a = fmaxf(a, __shfl_xor(a, m, 64));
    if (ln == 0) red[wv] = a;
    __syncthreads();
    a = fmaxf(fmaxf(red[0], red[1]), fmaxf(red[2], red[3]));
    float scale = (a > 0.f) ? a * (1.f / 127.f) : 1.f;
    int q = (int)rintf(w / scale);
    q = q > 127 ? 127 : (q < -127 ? -127 : q);
    // MFMA-B layout (in-wave gates, r10-verified): gate g, col j, k.
    // wave = j>>5; tt=(j>>4)&1; frag f=(g*2+tt)*4+(k>>6);
    // lane = ((k&63)>>4)*16 + (j&15); byte = k&15.
    {
      int g = which, j = col, k = t;
      int wavw = j >> 5;
      int lane = ((k & 63) >> 4) * 16 + (j & 15);
      int tt = (j >> 4) & 1;
      int f = (g * 2 + tt) * 4 + (k >> 6);
      size_t dst = (size_t)(wavw * 64 + lane) * 512 + (size_t)f * 16 + (size_t)(k & 15);
      wq[dst] = (signed char)q;
    }
    if (t == 0) sw[J] = scale;
  } else {
    for (int idx = t; idx < 256 * 96; idx += 256) {
      int j = idx / 96, d = idx % 96;
      float v = (d < DD) ? proj_W[d * 256 + j] : 0.f;
      PWT[idx] = f2bf(v);
    }
    float gw = head_g[t] * head_W[t];
    gW[t] = gw;
    float bw = head_b[t] * head_W[t];
    float s1 = gw, s2 = bw;
    for (int m = 32; m >= 1; m >>= 1) { s1 += __shfl_xor(s1, m, 64); s2 += __shfl_xor(s2, m, 64); }
    if (ln == 0) { red[wv] = s1; red[4 + wv] = s2; }
    __syncthreads();
    if (t == 0) {
      scal[0] = red[0] + red[1] + red[2] + red[3];
      scal[1] = red[4] + red[5] + red[6] + red[7] + head_bias[0];
    }
  }
}

// ---------------------------------------------------------------- k2: x -> feat
__global__ __launch_bounds__(512) void feat_kernel(
    const float* __restrict__ x, const float* __restrict__ ln_in_g, const float* __restrict__ ln_in_b,
    const float* __restrict__ proj_b, const float* __restrict__ ln_p_g, const float* __restrict__ ln_p_b,
    const unsigned short* __restrict__ PWT, unsigned short* __restrict__ feat,
    int s0, int C, int cshift)
{
  __shared__ __align__(16) unsigned short XA[64 * 104];
  __shared__ __align__(16) unsigned short XB[256 * 96];
  __shared__ float partS[64][4], partQ[64][4], statM[64], statI[64];
  int tid = threadIdx.x, w = tid >> 6, lane = tid & 63;
  int r0 = blockIdx.x * 64;

  {
    float g1v = (lane < 67) ? ln_in_g[lane] : 0.f;
    float b1v = (lane < 67) ? ln_in_b[lane] : 0.f;
    float g2v = (lane < 3) ? ln_in_g[64 + lane] : 0.f;
    float b2v = (lane < 3) ? ln_in_b[64 + lane] : 0.f;
    for (int i = 0; i < 8; ++i) {
      int rl = w * 8 + i;
      int r = r0 + rl;
      int bb = r >> cshift, cs = r & (C - 1);
      const float* xr = x + (size_t)(bb * SS + s0 + cs) * DD;
      float v0 = (lane < 67) ? xr[lane] : 0.f;
      float v1 = (lane < 3) ? xr[64 + lane] : 0.f;
      float s = v0 + v1, q = v0 * v0 + v1 * v1;
      for (int m = 32; m >= 1; m >>= 1) { s += __shfl_xor(s, m, 64); q += __shfl_xor(q, m, 64); }
      float mean = s * (1.f / 67.f);
      float var = q * (1.f / 67.f) - mean * mean;
      float inv = rsqrtf(var + 1e-5f);
      float xn0 = (v0 - mean) * inv * g1v + b1v;
      float xn1 = (v1 - mean) * inv * g2v + b2v;
      XA[rl * 104 + lane] = (lane < 67) ? f2bf(xn0) : (unsigned short)0;
      if (lane < 40) XA[rl * 104 + 64 + lane] = (lane < 3) ? f2bf(xn1) : (unsigned short)0;
    }
  }
  {
    const unsigned int* src = (const unsigned int*)PWT;
    unsigned int* dst = (unsigned int*)XB;
    for (int idx = tid; idx < 256 * 48; idx += 512) dst[idx] = src[idx];
  }
  __syncthreads();

  int wm = w >> 2, wn = w & 3;
  f32x4 acc[2][4];
  #pragma unroll
  for (int mt = 0; mt < 2; ++mt)
    #pragma unroll
    for (int nt = 0; nt < 4; ++nt) acc[mt][nt] = (f32x4){0.f, 0.f, 0.f, 0.f};
  #pragma unroll
  for (int ks = 0; ks < 3; ++ks) {
    int k = ks * 32 + (lane >> 4) * 8;
    bf16x8 a[2], b[4];
    #pragma unroll
    for (int mt = 0; mt < 2; ++mt) {
      int row = wm * 32 + mt * 16 + (lane & 15);
      a[mt] = *reinterpret_cast<const bf16x8*>(&XA[row * 104 + k]);
    }
    #pragma unroll
    for (int nt = 0; nt < 4; ++nt) {
      int col = wn * 64 + nt * 16 + (lane & 15);
      b[nt] = *reinterpret_cast<const bf16x8*>(&XB[col * 96 + k]);
    }
    #pragma unroll
    for (int mt = 0; mt < 2; ++mt)
      #pragma unroll
      for (int nt = 0; nt < 4; ++nt)
        acc[mt][nt] = __builtin_amdgcn_mfma_f32_16x16x32_bf16(a[mt], b[nt], acc[mt][nt], 0, 0, 0);
  }
  #pragma unroll
  for (int nt = 0; nt < 4; ++nt) {
    int col = wn * 64 + nt * 16 + (lane & 15);
    float pb = proj_b[col];
    #pragma unroll
    for (int mt = 0; mt < 2; ++mt)
      #pragma unroll
      for (int r = 0; r < 4; ++r) acc[mt][nt][r] += pb;
  }
  #pragma unroll
  for (int mt = 0; mt < 2; ++mt) {
    #pragma unroll
    for (int r = 0; r < 4; ++r) {
      float s = 0.f, q = 0.f;
      #pragma unroll
      for (int nt = 0; nt < 4; ++nt) { float v = acc[mt][nt][r]; s += v; q += v * v; }
      for (int m = 1; m < 16; m <<= 1) { s += __shfl_xor(s, m, 16); q += __shfl_xor(q, m, 16); }
      if ((lane & 15) == 0) {
        int row = wm * 32 + mt * 16 + (lane >> 4) * 4 + r;
        partS[row][wn] = s; partQ[row][wn] = q;
      }
    }
  }
  __syncthreads();
  if (tid < 64) {
    float s = partS[tid][0] + partS[tid][1] + partS[tid][2] + partS[tid][3];
    float q = partQ[tid][0] + partQ[tid][1] + partQ[tid][2] + partQ[tid][3];
    float mean = s * (1.f / 256.f);
    float var = q * (1.f / 256.f) - mean * mean;
    statM[tid] = mean; statI[tid] = rsqrtf(var + 1e-5f);
  }
  __syncthreads();
  #pragma unroll
  for (int nt = 0; nt < 4; ++nt) {
    int col = wn * 64 + nt * 16 + (lane & 15);
    float gc = ln_p_g[col], bc = ln_p_b[col];
    #pragma unroll
    for (int mt = 0; mt < 2; ++mt)
      #pragma unroll
      for (int r = 0; r < 4; ++r) {
        int row = wm * 32 + mt * 16 + (lane >> 4) * 4 + r;
        float v = acc[mt][nt][r];
        float y = (v - statM[row]) * statI[row] * gc + bc;
        float sl = y * sigm(y);
        feat[(size_t)(r0 + row) * 256 + col] = f2bf(sl);
      }
  }
}

// ---------------------------------------------------------------- k3: pre = feat @ WxT + bias4
__global__ __launch_bounds__(256, 2) void gemm_kernel(
    const unsigned short* __restrict__ feat, const unsigned short* __restrict__ WxT,
    const float* __restrict__ bias4, unsigned short* __restrict__ pre)
{
  __shared__ __align__(16) unsigned short Abuf[128 * 64];
  __shared__ __align__(16) unsigned short Bbuf[128 * 64];
  int tid = threadIdx.x, w = tid >> 6, lane = tid & 63;
  int m0 = blockIdx.x * 128, n0 = blockIdx.y * 128;
  int wm = w >> 1, wn = w & 1;
  f32x4 acc[4][4];
  #pragma unroll
  for (int i = 0; i < 4; ++i)
    #pragma unroll
    for (int j = 0; j < 4; ++j) acc[i][j] = (f32x4){0.f, 0.f, 0.f, 0.f};

  #pragma unroll 1
  for (int ks = 0; ks < 4; ++ks) {
    int k0 = ks * 64;
    #pragma unroll
    for (int i = 0; i < 4; ++i) {
      int c = i * 256 + tid;
      int row = c >> 3, cc = c & 7;
      const unsigned short* ga = feat + (size_t)(m0 + row) * 256 + (k0 + cc * 8);
      const unsigned short* gb = WxT + (size_t)(n0 + row) * 256 + (k0 + cc * 8);
      char* la = (char*)Abuf + (size_t)(i * 256 + w * 64) * 16;
      char* lb = (char*)Bbuf + (size_t)(i * 256 + w * 64) * 16;
      GLD_LDS16(ga, la);
      GLD_LDS16(gb, lb);
    }
    __syncthreads();
    #pragma unroll
    for (int kk = 0; kk < 2; ++kk) {
      int k = kk * 32 + (lane >> 4) * 8;
      bf16x8 a[4], b[4];
      #pragma unroll
      for (int mt = 0; mt < 4; ++mt) {
        int row = wm * 64 + mt * 16 + (lane & 15);
        a[mt] = *reinterpret_cast<const bf16x8*>(&Abuf[row * 64 + k]);
      }
      #pragma unroll
      for (int nt = 0; nt < 4; ++nt) {
        int col = wn * 64 + nt * 16 + (lane & 15);
        b[nt] = *reinterpret_cast<const bf16x8*>(&Bbuf[col * 64 + k]);
      }
      #pragma unroll
      for (int mt = 0; mt < 4; ++mt)
        #pragma unroll
        for (int nt = 0; nt < 4; ++nt)
          acc[mt][nt] = __builtin_amdgcn_mfma_f32_16x16x32_bf16(a[mt], b[nt], acc[mt][nt], 0, 0, 0);
    }
    __syncthreads();
  }
  #pragma unroll
  for (int nt = 0; nt < 4; ++nt) {
    int col = n0 + wn * 64 + nt * 16 + (lane & 15);
    float bv = bias4[col];
    #pragma unroll
    for (int mt = 0; mt < 4; ++mt)
      #pragma unroll
      for (int r = 0; r < 4; ++r) {
        int row = m0 + wm * 64 + mt * 16 + (lane >> 4) * 4 + r;
        pre[(size_t)row * 1024 + col] = f2bf(acc[mt][nt][r] + bv);
      }
  }
}

// ---------------------------------------------------------------- k4: recurrent scan, 1 WG/batch
// Wave w owns cols [w*32,(w+1)*32) x all 4 gates. B fragments in physical AGPRs:
// frag f=(g*2+tt) at a[f*16+kt*4 .. +3]. Per step: A = h broadcast, 32 MFMA; gate phase
// reads own c regs; ONE raw barrier/step (lgkmcnt-only wait -> global stores stay in flight).
#define WRA(n, val) asm volatile("v_accvgpr_write_b32 a" #n ", %0" :: "v"(val) : "a" #n)
#define WR4(n0,n1,n2,n3, q) \
  do { WRA(n0,(q).x); WRA(n1,(q).y); WRA(n2,(q).z); WRA(n3,(q).w); } while (0)
#define MFMA_AB(acc, af, b0, b1) \
  asm volatile("v_mfma_i32_16x16x64_i8 %0, %1, a[" #b0 ":" #b1 "], %2" \
               : "=&v"(acc) : "v"(af), "v"(acc))

__global__ __attribute__((amdgpu_flat_work_group_size(512, 512)))
           __attribute__((amdgpu_waves_per_eu(2, 2)))
void scan_kernel(
    const unsigned short* __restrict__ pre, const float* __restrict__ dt,
    const signed char* __restrict__ wq, const float* __restrict__ sw,
    int* __restrict__ hstate, unsigned short* __restrict__ hseq, int s0, int C)
{
  __shared__ __align__(16) signed char hq2[2][256];
  int tid = threadIdx.x, w = tid >> 6, l = tid & 63;
  int b = blockIdx.x;

  // stage 128 weight dwords (32 B-fragments) into physical AGPRs a0..a127
  {
    const int4* wp = (const int4*)(wq + (size_t)tid * 512);
    int4 q0, q1, q2, q3, q4, q5, q6, q7;
    q0=wp[0]; q1=wp[1]; q2=wp[2]; q3=wp[3]; q4=wp[4]; q5=wp[5]; q6=wp[6]; q7=wp[7];
    WR4(0,1,2,3,q0);     WR4(4,5,6,7,q1);     WR4(8,9,10,11,q2);    WR4(12,13,14,15,q3);
    WR4(16,17,18,19,q4); WR4(20,21,22,23,q5); WR4(24,25,26,27,q6);  WR4(28,29,30,31,q7);
    q0=wp[8]; q1=wp[9]; q2=wp[10]; q3=wp[11]; q4=wp[12]; q5=wp[13]; q6=wp[14]; q7=wp[15];
    WR4(32,33,34,35,q0); WR4(36,37,38,39,q1); WR4(40,41,42,43,q2);  WR4(44,45,46,47,q3);
    WR4(48,49,50,51,q4); WR4(52,53,54,55,q5); WR4(56,57,58,59,q6);  WR4(60,61,62,63,q7);
    q0=wp[16]; q1=wp[17]; q2=wp[18]; q3=wp[19]; q4=wp[20]; q5=wp[21]; q6=wp[22]; q7=wp[23];
    WR4(64,65,66,67,q0); WR4(68,69,70,71,q1); WR4(72,73,74,75,q2);  WR4(76,77,78,79,q3);
    WR4(80,81,82,83,q4); WR4(84,85,86,87,q5); WR4(88,89,90,91,q6);  WR4(92,93,94,95,q7);
    q0=wp[24]; q1=wp[25]; q2=wp[26]; q3=wp[27]; q4=wp[28]; q5=wp[29]; q6=wp[30]; q7=wp[31];
    WR4(96,97,98,99,q0);   WR4(100,101,102,103,q1); WR4(104,105,106,107,q2); WR4(108,109,110,111,q3);
    WR4(112,113,114,115,q4); WR4(116,117,118,119,q5); WR4(120,121,122,123,q6); WR4(124,125,126,127,q7);
  }

  // gate-phase lanes: lg<2; tt=lg; col j = w*32 + tt*16 + (l&15)
  int lg = l >> 4;
  int tt = lg & 1;
  bool gact = (lg < 2);
  int j = w * 32 + tt * 16 + (l & 15);

  float sc0 = 0.f, sc1 = 0.f, sc2 = 0.f, sc3 = 0.f;
  unsigned short pu0 = 0, pu1 = 0, pu2 = 0, pu3 = 0;
  float dtc = 0.f;
  const unsigned short* preB = pre + (size_t)b * C * 1024;
  unsigned short* hsB = hseq + (size_t)b * C * 256;
  // incremental pointers (r13: no per-step cs* multiplies)
  const unsigned short* pn = preB + 1024;     // prefetch source for step cs+1
  const float* dtp = dt + (size_t)b * SS + s0 + 1;
  unsigned short* hsp = hsB;                  // store base for step cs
  if (gact) {
    sc0 = sw[j]       * (1.f / 127.f);
    sc1 = sw[256 + j] * (1.f / 127.f);
    sc2 = sw[512 + j] * (1.f / 127.f);
    sc3 = sw[768 + j] * (1.f / 127.f);
    pu0 = preB[j]; pu1 = preB[256 + j]; pu2 = preB[512 + j]; pu3 = preB[768 + j];
    dtc = dtp[-1] * 10.f;
  }

  if (tid < 64) ((int*)hq2[0])[tid] = (s0 == 0) ? 0 : hstate[b * 64 + tid];
  int cur = 0;
  __syncthreads();

  for (int cs = 0; cs < C; ++cs) {
    // A fragments: h broadcast, 16 bytes per 16-lane group per K-tile
    const signed char* hb = hq2[cur];
    int aoff = lg << 4;
    i32x4 A0 = *reinterpret_cast<const i32x4*>(hb + 0 * 64 + aoff);
    i32x4 A1 = *reinterpret_cast<const i32x4*>(hb + 1 * 64 + aoff);
    i32x4 A2 = *reinterpret_cast<const i32x4*>(hb + 2 * 64 + aoff);
    i32x4 A3 = *reinterpret_cast<const i32x4*>(hb + 3 * 64 + aoff);
    i32x4 c0 = {0,0,0,0}, c1 = {0,0,0,0}, c2 = {0,0,0,0}, c3 = {0,0,0,0};
    i32x4 c4 = {0,0,0,0}, c5 = {0,0,0,0}, c6 = {0,0,0,0}, c7 = {0,0,0,0};
    // c_f = fragment f=(g*2+tt); AGPR base = f*16 + kt*4
    MFMA_AB(c0, A0,   0,   3); MFMA_AB(c1, A0,  16,  19); MFMA_AB(c2, A0,  32,  35); MFMA_AB(c3, A0,  48,  51);
    MFMA_AB(c4, A0,  64,  67); MFMA_AB(c5, A0,  80,  83); MFMA_AB(c6, A0,  96,  99); MFMA_AB(c7, A0, 112, 115);
    MFMA_AB(c0, A1,   4,   7); MFMA_AB(c1, A1,  20,  23); MFMA_AB(c2, A1,  36,  39); MFMA_AB(c3, A1,  52,  55);
    MFMA_AB(c4, A1,  68,  71); MFMA_AB(c5, A1,  84,  87); MFMA_AB(c6, A1, 100, 103); MFMA_AB(c7, A1, 116, 119);
    MFMA_AB(c0, A2,   8,  11); MFMA_AB(c1, A2,  24,  27); MFMA_AB(c2, A2,  40,  43); MFMA_AB(c3, A2,  56,  59);
    MFMA_AB(c4, A2,  72,  75); MFMA_AB(c5, A2,  88,  91); MFMA_AB(c6, A2, 104, 107); MFMA_AB(c7, A2, 120, 123);
    MFMA_AB(c0, A3,  12,  15); MFMA_AB(c1, A3,  28,  31); MFMA_AB(c2, A3,  44,  47); MFMA_AB(c3, A3,  60,  63);
    MFMA_AB(c4, A3,  76,  79); MFMA_AB(c5, A3,  92,  95); MFMA_AB(c6, A3, 108, 111); MFMA_AB(c7, A3, 124, 127);
    asm volatile("s_nop 7\n\ts_nop 7\n\ts_nop 7");   // MFMA-D -> VALU read hazard margin
    if (gact) {
      int d0 = tt ? c1.x : c0.x;
      int d1 = tt ? c3.x : c2.x;
      int d2 = tt ? c5.x : c4.x;
      int d3 = tt ? c7.x : c6.x;
      float g0 = (float)d0 * sc0 + bf2f(pu0);
      float g1 = (float)d1 * sc1 + bf2f(pu1);
      float g2 = (float)d2 * sc2 + bf2f(pu2);
      float g3 = (float)d3 * sc3 + bf2f(pu3);
      float f1 = tanh_f(g0), f2 = tanh_f(g1);
      float ti = sigm(g2 * dtc + g3);
      float h = f1 + ti * (f2 - f1);
      int q = (int)rintf(h * 127.f);
      q = q > 127 ? 127 : (q < -127 ? -127 : q);
      hq2[cur ^ 1][j] = (signed char)q;
      hsp[j] = f2bf(h);
      if (cs + 1 < C) {   // prefetch next step (stays in flight across the barrier)
        pu0 = pn[j]; pu1 = pn[256 + j]; pu2 = pn[512 + j]; pu3 = pn[768 + j];
        dtc = dtp[0] * 10.f;
      }
    }
    pn += 1024; dtp += 1; hsp += 256;
    cur ^= 1;
    // Counted-wait barrier (T4): only the LDS h-write must be visible; hseq global
    // stores + pre prefetch loads stay in flight (__syncthreads would vmcnt(0)-drain).
    asm volatile("s_waitcnt lgkmcnt(0)" ::: "memory");
    __builtin_amdgcn_sched_barrier(0);
    __builtin_amdgcn_s_barrier();
  }
  if (tid < 64) hstate[b * 64 + tid] = ((const int*)hq2[cur])[tid];
}

// ---------------------------------------------------------------- k5: head from hseq
__global__ __launch_bounds__(256) void head_kernel(
    const unsigned short* __restrict__ hseq, const float* __restrict__ gW,
    const float* __restrict__ scal, float* __restrict__ out, int s0, int C, int cshift)
{
  int tid = threadIdx.x, wv = tid >> 6, l = tid & 63;
  int row = blockIdx.x * 4 + wv;                 // row in [0, B*C)
  const unsigned short* hr = hseq + (size_t)row * 256 + l * 4;
  ushort4 u = *reinterpret_cast<const ushort4*>(hr);
  float4 gw = *reinterpret_cast<const float4*>(gW + l * 4);
  float v0 = bf2f(u.x), v1 = bf2f(u.y), v2 = bf2f(u.z), v3 = bf2f(u.w);
  float s1 = v0 + v1 + v2 + v3;
  float s2 = v0 * v0 + v1 * v1 + v2 * v2 + v3 * v3;
  float s3 = v0 * gw.x + v1 * gw.y + v2 * gw.z + v3 * gw.w;
  for (int m = 32; m >= 1; m >>= 1) {
    s1 += __shfl_xor(s1, m, 64); s2 += __shfl_xor(s2, m, 64); s3 += __shfl_xor(s3, m, 64);
  }
  if (l == 0) {
    float mean = s1 * (1.f / 256.f);
    float var = s2 * (1.f / 256.f) - mean * mean;
    float inv = rsqrtf(var + 1e-5f);
    int b = row >> cshift, cs = row & (C - 1);
    out[(size_t)b * SS + s0 + cs] = inv * (s3 - mean * scal[0]) + scal[1];
  }
}

// ---------------------------------------------------------------- launch
extern "C" void kernel_launch(void* const* d_in, const int* in_sizes, int n_in,
                              void* d_out, int out_size, void* d_ws, size_t ws_size,
                              hipStream_t stream)
{
  (void)in_sizes; (void)n_in; (void)out_size;
  const float* x        = (const float*)d_in[0];
  const float* dt       = (const float*)d_in[1];
  const float* ln_in_g  = (const float*)d_in[2];
  const float* ln_in_b  = (const float*)d_in[3];
  const float* proj_W   = (const float*)d_in[4];
  const float* proj_b   = (const float*)d_in[5];
  const float* ln_p_g   = (const float*)d_in[6];
  const float* ln_p_b   = (const float*)d_in[7];
  const float* W_ff1    = (const float*)d_in[8];
  const float* b_ff1    = (const float*)d_in[9];
  const float* W_ff2    = (const float*)d_in[10];
  const float* b_ff2    = (const float*)d_in[11];
  const float* W_ta     = (const float*)d_in[12];
  const float* b_ta     = (const float*)d_in[13];
  const float* W_tb     = (const float*)d_in[14];
  const float* b_tb     = (const float*)d_in[15];
  const float* head_g   = (const float*)d_in[16];
  const float* head_b   = (const float*)d_in[17];
  const float* head_W   = (const float*)d_in[18];
  const float* head_bias= (const float*)d_in[19];

  char* ws = (char*)d_ws;
  unsigned short* WxT = (unsigned short*)(ws + OFF_WXT);
  signed char* wq     = (signed char*)(ws + OFF_WQ);
  float* sw           = (float*)(ws + OFF_SW);
  float* bias4        = (float*)(ws + OFF_BIAS4);
  unsigned short* PWT = (unsigned short*)(ws + OFF_PWT);
  float* gWv          = (float*)(ws + OFF_GW);
  float* scal         = (float*)(ws + OFF_SCAL);
  int* hstate         = (int*)(ws + OFF_HST);

  int C = 16;
  for (int c = 2048; c >= 16; c >>= 1) {
    size_t need = OFF_FEAT + (size_t)c * 65536 + (size_t)c * 262144;
    if (need <= ws_size) { C = c; break; }
  }
  unsigned short* featb = (unsigned short*)(ws + OFF_FEAT);   // feat, then hseq
  unsigned short* preb  = (unsigned short*)(ws + OFF_FEAT + (size_t)C * 65536);
  int cshift = 31 - __builtin_clz((unsigned)C);

  prep_kernel<<<2049, 256, 0, stream>>>(proj_W, W_ff1, b_ff1, W_ff2, b_ff2, W_ta, b_ta, W_tb, b_tb,
                                        head_g, head_b, head_W, head_bias,
                                        WxT, wq, sw, bias4, PWT, gWv, scal);
  int nch = SS / C;
  for (int ch = 0; ch < nch; ++ch) {
    int s0 = ch * C;
    feat_kernel<<<dim3(BB * C / 64), 512, 0, stream>>>(x, ln_in_g, ln_in_b, proj_b, ln_p_g, ln_p_b,
                                                       PWT, featb, s0, C, cshift);
    gemm_kernel<<<dim3(BB * C / 128, 8), 256, 0, stream>>>(featb, WxT, bias4, preb);
    scan_kernel<<<dim3(BB), 512, 0, stream>>>(preb, dt, wq, sw, hstate, featb, s0, C);
    head_kernel<<<dim3(BB * C / 4), 256, 0, stream>>>(featb, gWv, scal, (float*)d_out, s0, C, cshift);
  }
}